// Round 1
// baseline (433.740 us; speedup 1.0000x reference)
//
#include <hip/hip_runtime.h>
#include <hip/hip_bf16.h>

#define NTOK 4096
#define HID 2048
#define INTER 1408
#define NEXP 8
#define NPAIR 8192   // NTOK * TOP_K

typedef short bf16x8 __attribute__((ext_vector_type(8)));
typedef float f32x4 __attribute__((ext_vector_type(4)));

__device__ __forceinline__ unsigned short f2bf(float f) {
  unsigned u = __builtin_bit_cast(unsigned, f);
  u += 0x7fffu + ((u >> 16) & 1u);   // round-to-nearest-even
  return (unsigned short)(u >> 16);
}

__device__ __forceinline__ void gload16(const void* g, void* l) {
  __builtin_amdgcn_global_load_lds(
      (const __attribute__((address_space(1))) void*)g,
      (__attribute__((address_space(3))) void*)l, 16, 0, 0);
}

// ---------------- fp32 -> bf16 convert ----------------
__global__ void k_cvt(const float* __restrict__ s, unsigned short* __restrict__ d, int n4) {
  int i = blockIdx.x * blockDim.x + threadIdx.x;
  int stride = gridDim.x * blockDim.x;
  for (; i < n4; i += stride) {
    float4 v = reinterpret_cast<const float4*>(s)[i];
    ushort4 o;
    o.x = f2bf(v.x); o.y = f2bf(v.y); o.z = f2bf(v.z); o.w = f2bf(v.w);
    reinterpret_cast<ushort4*>(d)[i] = o;
  }
}

// ---------------- routing ----------------
// ctrl layout (ints): [0..7]=cnt  [8..15]=cnt2  [16..23]=offs
__global__ void k_count(const int* __restrict__ ids, int* __restrict__ ctrl) {
  int p = blockIdx.x * blockDim.x + threadIdx.x;
  if (p < NPAIR) atomicAdd(&ctrl[ids[p]], 1);
}

__global__ void k_scan(int* __restrict__ ctrl) {
  if (threadIdx.x == 0) {
    int acc = 0;
    for (int e = 0; e < NEXP; ++e) { ctrl[16 + e] = acc; acc += ctrl[e]; }
  }
}

__global__ void k_fill(const int* __restrict__ ids, const float* __restrict__ wts,
                       int* __restrict__ ctrl, int* __restrict__ row_token,
                       float* __restrict__ row_weight) {
  int p = blockIdx.x * blockDim.x + threadIdx.x;
  if (p < NPAIR) {
    int e = ids[p];
    int pos = atomicAdd(&ctrl[8 + e], 1);
    int r = ctrl[16 + e] + pos;
    row_token[r] = p >> 1;
    row_weight[r] = wts[p];
  }
}

// ---------------- GEMM1: gate_up + SwiGLU ----------------
// A: gathered hidden rows [rows x 2048] bf16 ; B: w1[e] (2816 x 2048, K-major)
// Block: 128 rows x 128 act-cols (= 256 gate_up channels), BK=64, 8 waves.
__global__ __launch_bounds__(512) void k_gemm1(
    const unsigned short* __restrict__ hs,
    const unsigned short* __restrict__ w1,
    const int* __restrict__ ctrl,
    const int* __restrict__ row_token,
    unsigned short* __restrict__ act) {
  const int e = blockIdx.z;
  const int rows = ctrl[e];
  const int mt = blockIdx.y;
  if (mt * 128 >= rows) return;
  const int n0 = blockIdx.x * 128;
  const int off_e = ctrl[16 + e];

  __shared__ unsigned short smem[(128 + 256) * 64];
  unsigned short* As = smem;             // [128][64], chunk-swizzled
  unsigned short* Bs = smem + 128 * 64;  // [256][64] (gate 0..127, up 128..255)

  const int t = threadIdx.x;
  const int lane = t & 63;
  const int wv = t >> 6;
  const int wm = wv >> 2;   // 0..1  (64-row half)
  const int wn = wv & 3;    // 0..3  (32-col quarter)

  // staging source pointers (pre-swizzled global source, linear LDS dest)
  const unsigned short* a_src[2];
#pragma unroll
  for (int ld = 0; ld < 2; ++ld) {
    int idx = ld * 512 + t;
    int row = idx >> 3, chunk = idx & 7;
    int sc = chunk ^ (row & 7);
    int grow = mt * 128 + row;
    if (grow > rows - 1) grow = rows - 1;
    int token = row_token[off_e + grow];
    a_src[ld] = hs + (size_t)token * HID + sc * 8;
  }
  const unsigned short* b_src[4];
#pragma unroll
  for (int ld = 0; ld < 4; ++ld) {
    int idx = ld * 512 + t;
    int chan = idx >> 3, chunk = idx & 7;
    int sc = chunk ^ (chan & 7);
    int c = (chan < 128) ? (n0 + chan) : (INTER + n0 + chan - 128);
    b_src[ld] = w1 + (size_t)e * (2 * INTER * HID) + (size_t)c * HID + sc * 8;
  }
  unsigned short* a_dst[2];
  unsigned short* b_dst[4];
  {
    int wb = t & 448;  // wave-uniform
#pragma unroll
    for (int ld = 0; ld < 2; ++ld) a_dst[ld] = As + (ld * 512 + wb) * 8;
#pragma unroll
    for (int ld = 0; ld < 4; ++ld) b_dst[ld] = Bs + (ld * 512 + wb) * 8;
  }

  const f32x4 zz = {0.f, 0.f, 0.f, 0.f};
  f32x4 accg[4][2], accu[4][2];
#pragma unroll
  for (int m = 0; m < 4; ++m)
#pragma unroll
    for (int n = 0; n < 2; ++n) { accg[m][n] = zz; accu[m][n] = zz; }

  for (int k0 = 0; k0 < HID; k0 += 64) {
#pragma unroll
    for (int ld = 0; ld < 2; ++ld) gload16(a_src[ld] + k0, a_dst[ld]);
#pragma unroll
    for (int ld = 0; ld < 4; ++ld) gload16(b_src[ld] + k0, b_dst[ld]);
    __syncthreads();

    bf16x8 af[4][2], bg[2][2], bu[2][2];
#pragma unroll
    for (int m = 0; m < 4; ++m)
#pragma unroll
      for (int kk = 0; kk < 2; ++kk) {
        int row = wm * 64 + m * 16 + (lane & 15);
        int ch = (kk * 4 + (lane >> 4)) ^ (row & 7);
        af[m][kk] = *(const bf16x8*)(As + row * 64 + ch * 8);
      }
#pragma unroll
    for (int n = 0; n < 2; ++n)
#pragma unroll
      for (int kk = 0; kk < 2; ++kk) {
        int cg = wn * 32 + n * 16 + (lane & 15);
        int ch = (kk * 4 + (lane >> 4)) ^ (cg & 7);
        bg[n][kk] = *(const bf16x8*)(Bs + cg * 64 + ch * 8);
        bu[n][kk] = *(const bf16x8*)(Bs + (128 + cg) * 64 + ch * 8);
      }
#pragma unroll
    for (int kk = 0; kk < 2; ++kk)
#pragma unroll
      for (int m = 0; m < 4; ++m)
#pragma unroll
        for (int n = 0; n < 2; ++n) {
          accg[m][n] = __builtin_amdgcn_mfma_f32_16x16x32_bf16(af[m][kk], bg[n][kk], accg[m][n], 0, 0, 0);
          accu[m][n] = __builtin_amdgcn_mfma_f32_16x16x32_bf16(af[m][kk], bu[n][kk], accu[m][n], 0, 0, 0);
        }
    __syncthreads();
  }

#pragma unroll
  for (int m = 0; m < 4; ++m)
#pragma unroll
    for (int n = 0; n < 2; ++n) {
      int col = n0 + wn * 32 + n * 16 + (lane & 15);
#pragma unroll
      for (int j = 0; j < 4; ++j) {
        int grow = mt * 128 + wm * 64 + m * 16 + (lane >> 4) * 4 + j;
        if (grow < rows) {
          float g = accg[m][n][j];
          float u = accu[m][n][j];
          float a = g / (1.0f + __expf(-g)) * u;
          act[(size_t)(off_e + grow) * INTER + col] = f2bf(a);
        }
      }
    }
}

// ---------------- GEMM2: down proj + weighted scatter ----------------
// A: act rows (contiguous per expert) [rows x 1408] ; B: w2[e] (2048 x 1408, K-major)
__global__ __launch_bounds__(512) void k_gemm2(
    const unsigned short* __restrict__ act,
    const unsigned short* __restrict__ w2,
    const int* __restrict__ ctrl,
    const int* __restrict__ row_token,
    const float* __restrict__ row_weight,
    float* __restrict__ out) {
  const int e = blockIdx.z;
  const int rows = ctrl[e];
  const int mt = blockIdx.y;
  if (mt * 128 >= rows) return;
  const int n0 = blockIdx.x * 128;
  const int off_e = ctrl[16 + e];

  __shared__ unsigned short smem[(128 + 128) * 64];
  unsigned short* As = smem;
  unsigned short* Bs = smem + 128 * 64;

  const int t = threadIdx.x;
  const int lane = t & 63;
  const int wv = t >> 6;
  const int wm = wv >> 2;
  const int wn = wv & 3;

  const unsigned short* a_src[2];
#pragma unroll
  for (int ld = 0; ld < 2; ++ld) {
    int idx = ld * 512 + t;
    int row = idx >> 3, chunk = idx & 7;
    int sc = chunk ^ (row & 7);
    int grow = mt * 128 + row;
    if (grow > rows - 1) grow = rows - 1;
    a_src[ld] = act + (size_t)(off_e + grow) * INTER + sc * 8;
  }
  const unsigned short* b_src[2];
#pragma unroll
  for (int ld = 0; ld < 2; ++ld) {
    int idx = ld * 512 + t;
    int chan = idx >> 3, chunk = idx & 7;
    int sc = chunk ^ (chan & 7);
    b_src[ld] = w2 + (size_t)e * (HID * INTER) + (size_t)(n0 + chan) * INTER + sc * 8;
  }
  unsigned short* a_dst[2];
  unsigned short* b_dst[2];
  {
    int wb = t & 448;
#pragma unroll
    for (int ld = 0; ld < 2; ++ld) {
      a_dst[ld] = As + (ld * 512 + wb) * 8;
      b_dst[ld] = Bs + (ld * 512 + wb) * 8;
    }
  }

  const f32x4 zz = {0.f, 0.f, 0.f, 0.f};
  f32x4 acc[4][2];
#pragma unroll
  for (int m = 0; m < 4; ++m)
#pragma unroll
    for (int n = 0; n < 2; ++n) acc[m][n] = zz;

  for (int k0 = 0; k0 < INTER; k0 += 64) {
#pragma unroll
    for (int ld = 0; ld < 2; ++ld) gload16(a_src[ld] + k0, a_dst[ld]);
#pragma unroll
    for (int ld = 0; ld < 2; ++ld) gload16(b_src[ld] + k0, b_dst[ld]);
    __syncthreads();

    bf16x8 af[4][2], bf[2][2];
#pragma unroll
    for (int m = 0; m < 4; ++m)
#pragma unroll
      for (int kk = 0; kk < 2; ++kk) {
        int row = wm * 64 + m * 16 + (lane & 15);
        int ch = (kk * 4 + (lane >> 4)) ^ (row & 7);
        af[m][kk] = *(const bf16x8*)(As + row * 64 + ch * 8);
      }
#pragma unroll
    for (int n = 0; n < 2; ++n)
#pragma unroll
      for (int kk = 0; kk < 2; ++kk) {
        int cg = wn * 32 + n * 16 + (lane & 15);
        int ch = (kk * 4 + (lane >> 4)) ^ (cg & 7);
        bf[n][kk] = *(const bf16x8*)(Bs + cg * 64 + ch * 8);
      }
#pragma unroll
    for (int kk = 0; kk < 2; ++kk)
#pragma unroll
      for (int m = 0; m < 4; ++m)
#pragma unroll
        for (int n = 0; n < 2; ++n)
          acc[m][n] = __builtin_amdgcn_mfma_f32_16x16x32_bf16(af[m][kk], bf[n][kk], acc[m][n], 0, 0, 0);
    __syncthreads();
  }

#pragma unroll
  for (int m = 0; m < 4; ++m)
#pragma unroll
    for (int n = 0; n < 2; ++n) {
      int col = n0 + wn * 32 + n * 16 + (lane & 15);
#pragma unroll
      for (int j = 0; j < 4; ++j) {
        int grow = mt * 128 + wm * 64 + m * 16 + (lane >> 4) * 4 + j;
        if (grow < rows) {
          int r = off_e + grow;
          float v = acc[m][n][j] * row_weight[r];
          atomicAdd(&out[(size_t)row_token[r] * HID + col], v);
        }
      }
    }
}

extern "C" void kernel_launch(void* const* d_in, const int* in_sizes, int n_in,
                              void* d_out, int out_size, void* d_ws, size_t ws_size,
                              hipStream_t stream) {
  const float* hs_f = (const float*)d_in[0];
  const float* w1_f = (const float*)d_in[1];
  const float* w2_f = (const float*)d_in[2];
  const float* tw   = (const float*)d_in[3];
  const int*   tids = (const int*)d_in[4];
  float* out = (float*)d_out;

  // workspace layout (bytes)
  char* ws = (char*)d_ws;
  unsigned short* hs_b = (unsigned short*)(ws);                   // 16,777,216
  unsigned short* w1_b = (unsigned short*)(ws + 16777216);        // 92,274,688
  unsigned short* w2_b = (unsigned short*)(ws + 109051904);       // 46,137,344
  unsigned short* act  = (unsigned short*)(ws + 155189248);       // 23,068,672
  int*   ctrl       = (int*)(ws + 178257920);                     // 128
  int*   row_token  = (int*)(ws + 178258176);                     // 32,768
  float* row_weight = (float*)(ws + 178290944);                   // 32,768
  // total: 178,323,712 bytes

  hipMemsetAsync(d_out, 0, (size_t)NTOK * HID * sizeof(float), stream);
  hipMemsetAsync(ctrl, 0, 128, stream);

  k_cvt<<<2048, 256, 0, stream>>>(hs_f, hs_b, NTOK * HID / 4);
  k_cvt<<<4096, 256, 0, stream>>>(w1_f, w1_b, NEXP * 2 * INTER * HID / 4);
  k_cvt<<<4096, 256, 0, stream>>>(w2_f, w2_b, NEXP * HID * INTER / 4);

  k_count<<<NPAIR / 256, 256, 0, stream>>>(tids, ctrl);
  k_scan<<<1, 64, 0, stream>>>(ctrl);
  k_fill<<<NPAIR / 256, 256, 0, stream>>>(tids, tw, ctrl, row_token, row_weight);

  k_gemm1<<<dim3(INTER / 128, 64, NEXP), 512, 0, stream>>>(hs_b, w1_b, ctrl, row_token, act);
  k_gemm2<<<dim3(HID / 128, 64, NEXP), 512, 0, stream>>>(act, w2_b, ctrl, row_token, row_weight, out);
}

// Round 2
// 361.250 us; speedup vs baseline: 1.2007x; 1.2007x over previous
//
#include <hip/hip_runtime.h>
#include <hip/hip_bf16.h>

#define NTOK 4096
#define HID 2048
#define INTER 1408
#define NEXP 8
#define NPAIR 8192   // NTOK * TOP_K
#define NKT1 32      // HID/64
#define NKT2 22      // INTER/64

typedef short bf16x8 __attribute__((ext_vector_type(8)));
typedef float f32x4 __attribute__((ext_vector_type(4)));

__device__ __forceinline__ unsigned short f2bf(float f) {
  unsigned u = __builtin_bit_cast(unsigned, f);
  u += 0x7fffu + ((u >> 16) & 1u);   // round-to-nearest-even
  return (unsigned short)(u >> 16);
}
__device__ __forceinline__ float bf2f(unsigned short v) {
  return __builtin_bit_cast(float, (unsigned)v << 16);
}

__device__ __forceinline__ void gload16(const void* g, void* l) {
  __builtin_amdgcn_global_load_lds(
      (const __attribute__((address_space(1))) void*)g,
      (__attribute__((address_space(3))) void*)l, 16, 0, 0);
}

#define BAR __builtin_amdgcn_s_barrier()
#define LGKM0 asm volatile("s_waitcnt lgkmcnt(0)" ::: "memory")
#define VM6 asm volatile("s_waitcnt vmcnt(6)" ::: "memory")
#define VM0 asm volatile("s_waitcnt vmcnt(0)" ::: "memory")
#define PRIO1 __builtin_amdgcn_s_setprio(1)
#define PRIO0 __builtin_amdgcn_s_setprio(0)

// ---- stage one half-tile unit (2 x global_load_lds per thread) ----
// BB: LDS buffer base (0 or 32768 elems). A slots 0..255 -> elems 0..16383,
// B slots at +16384. Linear LDS dest (wave-uniform base + lane*16B); the
// chunk-XOR swizzle is applied on the per-lane GLOBAL source (rule #21).
#define STAGE_A(BB, u, ktile) \
  gload16(asrc[(u)*2+0] + (ktile)*64, lds + (BB) + ((u)*2+0)*4096 + wvb); \
  gload16(asrc[(u)*2+1] + (ktile)*64, lds + (BB) + ((u)*2+1)*4096 + wvb);
#define STAGE_B(BB, u, ktile) \
  gload16(bsrc[(u)*2+0] + (ktile)*64, lds + (BB) + 16384 + ((u)*2+0)*4096 + wvb); \
  gload16(bsrc[(u)*2+1] + (ktile)*64, lds + (BB) + 16384 + ((u)*2+1)*4096 + wvb);

// ---- ds_read one register half-subtile ----
#define READ_A(dst, BB, mh) \
  _Pragma("unroll") for (int m_ = 0; m_ < 4; ++m_) { \
    dst[m_][0] = *(const bf16x8*)(lds + (BB) + aoff + (mh)*8192 + m_*1024 + csw0); \
    dst[m_][1] = *(const bf16x8*)(lds + (BB) + aoff + (mh)*8192 + m_*1024 + csw1); \
  }
#define READ_B(dst, BB, nh) \
  _Pragma("unroll") for (int n_ = 0; n_ < 2; ++n_) { \
    dst[n_][0] = *(const bf16x8*)(lds + (BB) + boff + (nh)*8192 + n_*1024 + csw0); \
    dst[n_][1] = *(const bf16x8*)(lds + (BB) + boff + (nh)*8192 + n_*1024 + csw1); \
  }

// ---- 16 MFMA: one quadrant (Mhalf mh, Nhalf nh) x K=64 ----
#define MMA_Q(afr, bfr, mh, nh) \
  _Pragma("unroll") for (int m_ = 0; m_ < 4; ++m_) \
  _Pragma("unroll") for (int n_ = 0; n_ < 2; ++n_) { \
    acc[(mh)*4+m_][(nh)*2+n_] = __builtin_amdgcn_mfma_f32_16x16x32_bf16(afr[m_][0], bfr[n_][0], acc[(mh)*4+m_][(nh)*2+n_], 0, 0, 0); \
    acc[(mh)*4+m_][(nh)*2+n_] = __builtin_amdgcn_mfma_f32_16x16x32_bf16(afr[m_][1], bfr[n_][1], acc[(mh)*4+m_][(nh)*2+n_], 0, 0, 0); \
  }

// 8-phase body: phases 1-4 compute kt (buf0), 5-8 compute kt+1 (buf1).
// Stage schedule (unit staged the phase AFTER its LDS region's last ds_read):
// ph1:B1(kt+1) ph2:B0(kt+2) ph3:A0(kt+2) ph4:A1(kt+2)+VM6
// ph5:B1(kt+2) ph6:B0(kt+3) ph7:A0(kt+3) ph8:A1(kt+3)+VM6
#define EIGHT_PHASES(kt) \
  READ_A(afM0, 0, 0) READ_B(bfN0, 0, 0) STAGE_B(32768, 1, (kt)+1); \
  BAR; LGKM0; PRIO1; MMA_Q(afM0, bfN0, 0, 0) PRIO0; BAR; \
  READ_B(bfN1, 0, 1) STAGE_B(0, 0, (kt)+2); \
  BAR; LGKM0; PRIO1; MMA_Q(afM0, bfN1, 0, 1) PRIO0; BAR; \
  READ_A(afM1, 0, 1) STAGE_A(0, 0, (kt)+2); \
  BAR; LGKM0; PRIO1; MMA_Q(afM1, bfN1, 1, 1) PRIO0; BAR; \
  STAGE_A(0, 1, (kt)+2); \
  BAR; LGKM0; PRIO1; MMA_Q(afM1, bfN0, 1, 0) PRIO0; VM6; BAR; \
  READ_A(afM0, 32768, 0) READ_B(bfN0, 32768, 0) STAGE_B(0, 1, (kt)+2); \
  BAR; LGKM0; PRIO1; MMA_Q(afM0, bfN0, 0, 0) PRIO0; BAR; \
  READ_B(bfN1, 32768, 1) STAGE_B(32768, 0, (kt)+3); \
  BAR; LGKM0; PRIO1; MMA_Q(afM0, bfN1, 0, 1) PRIO0; BAR; \
  READ_A(afM1, 32768, 1) STAGE_A(32768, 0, (kt)+3); \
  BAR; LGKM0; PRIO1; MMA_Q(afM1, bfN1, 1, 1) PRIO0; BAR; \
  STAGE_A(32768, 1, (kt)+3); \
  BAR; LGKM0; PRIO1; MMA_Q(afM1, bfN0, 1, 0) PRIO0; VM6; BAR;

// Epilogue: compute last two K-tiles, no stages except B1(kt+1); drain at ph4.
#define EPI_PHASES(kt) \
  READ_A(afM0, 0, 0) READ_B(bfN0, 0, 0) STAGE_B(32768, 1, (kt)+1); \
  BAR; LGKM0; PRIO1; MMA_Q(afM0, bfN0, 0, 0) PRIO0; BAR; \
  READ_B(bfN1, 0, 1) \
  BAR; LGKM0; PRIO1; MMA_Q(afM0, bfN1, 0, 1) PRIO0; BAR; \
  READ_A(afM1, 0, 1) \
  BAR; LGKM0; PRIO1; MMA_Q(afM1, bfN1, 1, 1) PRIO0; BAR; \
  BAR; LGKM0; PRIO1; MMA_Q(afM1, bfN0, 1, 0) PRIO0; VM0; BAR; \
  READ_A(afM0, 32768, 0) READ_B(bfN0, 32768, 0) \
  BAR; LGKM0; PRIO1; MMA_Q(afM0, bfN0, 0, 0) PRIO0; BAR; \
  READ_B(bfN1, 32768, 1) \
  BAR; LGKM0; PRIO1; MMA_Q(afM0, bfN1, 0, 1) PRIO0; BAR; \
  READ_A(afM1, 32768, 1) \
  BAR; LGKM0; PRIO1; MMA_Q(afM1, bfN1, 1, 1) PRIO0; BAR; \
  LGKM0; PRIO1; MMA_Q(afM1, bfN0, 1, 0) PRIO0;

// ---------------- fp32 -> bf16 convert (all three inputs, one launch) ----
__global__ void k_cvt_all(const float* __restrict__ hs, const float* __restrict__ w1,
                          const float* __restrict__ w2, unsigned short* __restrict__ dst) {
  const int N0 = NTOK * HID / 4;
  const int N1 = N0 + NEXP * 2 * INTER * HID / 4;
  const int N2 = N1 + NEXP * HID * INTER / 4;
  int i = blockIdx.x * blockDim.x + threadIdx.x;
  int stride = gridDim.x * blockDim.x;
  for (; i < N2; i += stride) {
    const float* s; int o;
    if (i < N0) { s = hs; o = i; }
    else if (i < N1) { s = w1; o = i - N0; }
    else { s = w2; o = i - N1; }
    float4 v = reinterpret_cast<const float4*>(s)[o];
    ushort4 u;
    u.x = f2bf(v.x); u.y = f2bf(v.y); u.z = f2bf(v.z); u.w = f2bf(v.w);
    reinterpret_cast<ushort4*>(dst)[i] = u;
  }
}

// ---------------- routing ----------------
__global__ void k_count(const int* __restrict__ ids, int* __restrict__ ctrl) {
  int p = blockIdx.x * blockDim.x + threadIdx.x;
  if (p < NPAIR) atomicAdd(&ctrl[ids[p]], 1);
}
__global__ void k_scan(int* __restrict__ ctrl) {
  if (threadIdx.x == 0) {
    int acc = 0;
    for (int e = 0; e < NEXP; ++e) { ctrl[16 + e] = acc; acc += ctrl[e]; }
  }
}
__global__ void k_fill(const int* __restrict__ ids, int* __restrict__ ctrl,
                       int* __restrict__ row_token, int* __restrict__ inv_row) {
  int p = blockIdx.x * blockDim.x + threadIdx.x;
  if (p < NPAIR) {
    int e = ids[p];
    int pos = atomicAdd(&ctrl[8 + e], 1);
    int r = ctrl[16 + e] + pos;
    row_token[r] = p >> 1;
    inv_row[p] = r;
  }
}

// ---------------- GEMM1: gate_up + SwiGLU (8-phase, 256x(128 acts)) ------
__global__ __launch_bounds__(512, 2) void k_gemm1(
    const unsigned short* __restrict__ hs,
    const unsigned short* __restrict__ w1,
    const int* __restrict__ ctrl,
    const int* __restrict__ row_token,
    unsigned short* __restrict__ act) {
  const int e = blockIdx.z;
  const int rows = ctrl[e];
  const int mt = blockIdx.y;
  if (mt * 256 >= rows) return;
  const int n0g = blockIdx.x * 128;
  const int off_e = ctrl[16 + e];
  const unsigned short* w1e = w1 + (size_t)e * (2 * INTER * HID);

  __shared__ unsigned short smem[65536];  // 128 KiB: 2 bufs x (A 256x64 + B 256x64)
  unsigned short* lds = smem;

  const int t = threadIdx.x;
  const int lane = t & 63, wv = t >> 6;
  const int wm = wv >> 2, wn = wv & 3;
  const int lm = lane & 15, hi4 = lane >> 4;
  const int wvb = (t & 448) * 8;
  const int aoff = (wm * 64 + lm) * 64;
  const int boff = 16384 + (wn * 32 + lm) * 64;
  const int csw0 = ((hi4) ^ (lm & 7)) * 8;
  const int csw1 = ((4 + hi4) ^ (lm & 7)) * 8;

  // stage sources. A slot p: M0 rows of both wave-halves first (unit A0),
  // then M1 rows (unit A1): row r(p) = ((p>>6)&1)*128 + (p>>7)*64 + (p&63).
  const unsigned short* asrc[4];
#pragma unroll
  for (int i = 0; i < 4; ++i) {
    int p = i * 64 + (t >> 3);
    int r = ((p >> 6) & 1) * 128 + (p >> 7) * 64 + (p & 63);
    int grow = mt * 256 + r;
    if (grow > rows - 1) grow = rows - 1;
    int token = row_token[off_e + grow];
    asrc[i] = hs + (size_t)token * HID + ((t & 7) ^ (p & 7)) * 8;
  }
  // B slot p: nh=p>>7 (0=gate,1=up), wave wn=(p&127)>>5, idx=p&31 -> each
  // wave owns 32 act cols with both gate and up fragments (intra-wave SwiGLU).
  const unsigned short* bsrc[4];
#pragma unroll
  for (int i = 0; i < 4; ++i) {
    int p = i * 64 + (t >> 3);
    int nh = p >> 7, wns = (p & 127) >> 5, idx = p & 31;
    int c = n0g + wns * 32 + idx + nh * INTER;
    bsrc[i] = w1e + (size_t)c * HID + ((t & 7) ^ (p & 7)) * 8;
  }

  f32x4 acc[8][4];
#pragma unroll
  for (int i = 0; i < 8; ++i)
#pragma unroll
    for (int j = 0; j < 4; ++j) acc[i][j] = (f32x4){0.f, 0.f, 0.f, 0.f};
  bf16x8 afM0[4][2], afM1[4][2], bfN0[2][2], bfN1[2][2];

  // prologue: kt0 all 4 units + kt1 first 3; drain kt0 (vmcnt 6 = 3 units)
  STAGE_B(0, 0, 0) STAGE_A(0, 0, 0) STAGE_A(0, 1, 0) STAGE_B(0, 1, 0)
  STAGE_B(32768, 0, 1) STAGE_A(32768, 0, 1) STAGE_A(32768, 1, 1)
  VM6; BAR;

  for (int kt = 0; kt + 3 < NKT1; kt += 2) { EIGHT_PHASES(kt) }
  EPI_PHASES(NKT1 - 2)

  // SwiGLU epilogue: gate = acc[mf][n], up = acc[mf][2+n]
#pragma unroll
  for (int mh = 0; mh < 2; ++mh)
#pragma unroll
    for (int m = 0; m < 4; ++m)
#pragma unroll
      for (int n = 0; n < 2; ++n) {
        int col = n0g + wn * 32 + n * 16 + lm;
#pragma unroll
        for (int j = 0; j < 4; ++j) {
          int grow = mt * 256 + wm * 128 + mh * 64 + m * 16 + hi4 * 4 + j;
          if (grow < rows) {
            float g = acc[mh * 4 + m][n][j];
            float u = acc[mh * 4 + m][2 + n][j];
            float a = g / (1.0f + __expf(-g)) * u;
            act[(size_t)(off_e + grow) * INTER + col] = f2bf(a);
          }
        }
      }
}

// ---------------- GEMM2: down proj (8-phase, 256x256) --------------------
__global__ __launch_bounds__(512, 2) void k_gemm2(
    const unsigned short* __restrict__ act,
    const unsigned short* __restrict__ w2,
    const int* __restrict__ ctrl,
    unsigned short* __restrict__ eo) {
  const int e = blockIdx.z;
  const int rows = ctrl[e];
  const int mt = blockIdx.y;
  if (mt * 256 >= rows) return;
  const int n0 = blockIdx.x * 256;
  const int off_e = ctrl[16 + e];
  const unsigned short* w2e = w2 + (size_t)e * (HID * INTER);

  __shared__ unsigned short smem[65536];
  unsigned short* lds = smem;

  const int t = threadIdx.x;
  const int lane = t & 63, wv = t >> 6;
  const int wm = wv >> 2, wn = wv & 3;
  const int lm = lane & 15, hi4 = lane >> 4;
  const int wvb = (t & 448) * 8;
  const int aoff = (wm * 64 + lm) * 64;
  const int boff = 16384 + (wn * 32 + lm) * 64;
  const int csw0 = ((hi4) ^ (lm & 7)) * 8;
  const int csw1 = ((4 + hi4) ^ (lm & 7)) * 8;

  const unsigned short* asrc[4];
#pragma unroll
  for (int i = 0; i < 4; ++i) {
    int p = i * 64 + (t >> 3);
    int r = ((p >> 6) & 1) * 128 + (p >> 7) * 64 + (p & 63);
    int grow = mt * 256 + r;
    if (grow > rows - 1) grow = rows - 1;
    asrc[i] = act + (size_t)(off_e + grow) * INTER + ((t & 7) ^ (p & 7)) * 8;
  }
  const unsigned short* bsrc[4];
#pragma unroll
  for (int i = 0; i < 4; ++i) {
    int p = i * 64 + (t >> 3);
    int nh = p >> 7, wns = (p & 127) >> 5, idx = p & 31;
    int c = n0 + wns * 64 + nh * 32 + idx;
    bsrc[i] = w2e + (size_t)c * INTER + ((t & 7) ^ (p & 7)) * 8;
  }

  f32x4 acc[8][4];
#pragma unroll
  for (int i = 0; i < 8; ++i)
#pragma unroll
    for (int j = 0; j < 4; ++j) acc[i][j] = (f32x4){0.f, 0.f, 0.f, 0.f};
  bf16x8 afM0[4][2], afM1[4][2], bfN0[2][2], bfN1[2][2];

  STAGE_B(0, 0, 0) STAGE_A(0, 0, 0) STAGE_A(0, 1, 0) STAGE_B(0, 1, 0)
  STAGE_B(32768, 0, 1) STAGE_A(32768, 0, 1) STAGE_A(32768, 1, 1)
  VM6; BAR;

  for (int kt = 0; kt + 3 < NKT2; kt += 2) { EIGHT_PHASES(kt) }
  EPI_PHASES(NKT2 - 2)

#pragma unroll
  for (int mh = 0; mh < 2; ++mh)
#pragma unroll
    for (int m = 0; m < 4; ++m)
#pragma unroll
      for (int nh = 0; nh < 2; ++nh)
#pragma unroll
        for (int n = 0; n < 2; ++n) {
          int col = n0 + wn * 64 + nh * 32 + n * 16 + lm;
#pragma unroll
          for (int j = 0; j < 4; ++j) {
            int grow = mt * 256 + wm * 128 + mh * 64 + m * 16 + hi4 * 4 + j;
            if (grow < rows)
              eo[(size_t)(off_e + grow) * HID + col] = f2bf(acc[mh * 4 + m][nh * 2 + n][j]);
          }
        }
}

// ---------------- weighted combine: out = w0*eo[r0] + w1*eo[r1] ----------
__global__ void k_combine(const unsigned short* __restrict__ eo,
                          const float* __restrict__ tw,
                          const int* __restrict__ inv_row,
                          float* __restrict__ out) {
  int idx = blockIdx.x * blockDim.x + threadIdx.x;  // one bf16x8 chunk
  int tok = idx >> 8;        // HID/8 = 256 chunks per token
  int c8 = (idx & 255) * 8;
  int r0 = inv_row[tok * 2], r1 = inv_row[tok * 2 + 1];
  float w0 = tw[tok * 2], w1 = tw[tok * 2 + 1];
  bf16x8 v0 = *(const bf16x8*)(eo + (size_t)r0 * HID + c8);
  bf16x8 v1 = *(const bf16x8*)(eo + (size_t)r1 * HID + c8);
  float4 o0, o1;
  o0.x = w0 * bf2f((unsigned short)v0[0]) + w1 * bf2f((unsigned short)v1[0]);
  o0.y = w0 * bf2f((unsigned short)v0[1]) + w1 * bf2f((unsigned short)v1[1]);
  o0.z = w0 * bf2f((unsigned short)v0[2]) + w1 * bf2f((unsigned short)v1[2]);
  o0.w = w0 * bf2f((unsigned short)v0[3]) + w1 * bf2f((unsigned short)v1[3]);
  o1.x = w0 * bf2f((unsigned short)v0[4]) + w1 * bf2f((unsigned short)v1[4]);
  o1.y = w0 * bf2f((unsigned short)v0[5]) + w1 * bf2f((unsigned short)v1[5]);
  o1.z = w0 * bf2f((unsigned short)v0[6]) + w1 * bf2f((unsigned short)v1[6]);
  o1.w = w0 * bf2f((unsigned short)v0[7]) + w1 * bf2f((unsigned short)v1[7]);
  float4* op = reinterpret_cast<float4*>(out) + (size_t)tok * 512 + (idx & 255) * 2;
  op[0] = o0;
  op[1] = o1;
}

extern "C" void kernel_launch(void* const* d_in, const int* in_sizes, int n_in,
                              void* d_out, int out_size, void* d_ws, size_t ws_size,
                              hipStream_t stream) {
  const float* hs_f = (const float*)d_in[0];
  const float* w1_f = (const float*)d_in[1];
  const float* w2_f = (const float*)d_in[2];
  const float* tw   = (const float*)d_in[3];
  const int*   tids = (const int*)d_in[4];
  float* out = (float*)d_out;

  // workspace layout (bytes) — same 178,323,712-byte footprint as round 1.
  char* ws = (char*)d_ws;
  unsigned short* hs_b = (unsigned short*)(ws);                   // 16,777,216
  unsigned short* w1_b = (unsigned short*)(ws + 16777216);        // 92,274,688
  unsigned short* w2_b = (unsigned short*)(ws + 109051904);       // 46,137,344
  unsigned short* act  = (unsigned short*)(ws + 155189248);       // 23,068,672
  // eo overlays w1_b (dead after gemm1): 8192*2048*2 = 33,554,432 bytes
  unsigned short* eo   = (unsigned short*)(ws + 16777216);
  int* ctrl      = (int*)(ws + 178257920);                        // 256 B slot
  int* row_token = (int*)(ws + 178258176);                        // 32,768
  int* inv_row   = (int*)(ws + 178290944);                        // 32,768

  hipMemsetAsync(ctrl, 0, 128, stream);

  k_cvt_all<<<4096, 256, 0, stream>>>(hs_f, w1_f, w2_f, hs_b);

  k_count<<<NPAIR / 256, 256, 0, stream>>>(tids, ctrl);
  k_scan<<<1, 64, 0, stream>>>(ctrl);
  k_fill<<<NPAIR / 256, 256, 0, stream>>>(tids, ctrl, row_token, inv_row);

  k_gemm1<<<dim3(INTER / 128, 32, NEXP), 512, 0, stream>>>(hs_b, w1_b, ctrl, row_token, act);
  k_gemm2<<<dim3(HID / 256, 32, NEXP), 512, 0, stream>>>(act, w2_b, ctrl, eo);
  k_combine<<<NTOK * HID / 8 / 256, 256, 0, stream>>>(eo, tw, inv_row, out);
}

// Round 3
// 325.222 us; speedup vs baseline: 1.3337x; 1.1108x over previous
//
#include <hip/hip_runtime.h>
#include <hip/hip_bf16.h>

#define NTOK 4096
#define HID 2048
#define INTER 1408
#define NEXP 8
#define NPAIR 8192   // NTOK * TOP_K
#define NKT1 32      // HID/64
#define NKT2 22      // INTER/64
#define SZ1 24576    // gemm1 elems/buffer: A 128x64 + B 256x64
#define SZ2 16384    // gemm2 elems/buffer: A 128x64 + B 128x64

typedef short bf16x8 __attribute__((ext_vector_type(8)));
typedef float f32x4 __attribute__((ext_vector_type(4)));

__device__ __forceinline__ unsigned short f2bf(float f) {
  unsigned u = __builtin_bit_cast(unsigned, f);
  u += 0x7fffu + ((u >> 16) & 1u);   // round-to-nearest-even
  return (unsigned short)(u >> 16);
}
__device__ __forceinline__ float bf2f(unsigned short v) {
  return __builtin_bit_cast(float, (unsigned)v << 16);
}

__device__ __forceinline__ void gload16(const void* g, void* l) {
  __builtin_amdgcn_global_load_lds(
      (const __attribute__((address_space(1))) void*)g,
      (__attribute__((address_space(3))) void*)l, 16, 0, 0);
}

#define BAR __builtin_amdgcn_s_barrier()
#define LGKM0 asm volatile("s_waitcnt lgkmcnt(0)" ::: "memory")
#define VM6 asm volatile("s_waitcnt vmcnt(6)" ::: "memory")
#define VM0 asm volatile("s_waitcnt vmcnt(0)" ::: "memory")
#define PRIO1 __builtin_amdgcn_s_setprio(1)
#define PRIO0 __builtin_amdgcn_s_setprio(0)

// ---------------- fp32 -> bf16 convert (all three inputs, one launch) ----
__global__ void k_cvt_all(const float* __restrict__ hs, const float* __restrict__ w1,
                          const float* __restrict__ w2, unsigned short* __restrict__ dst) {
  const int N0 = NTOK * HID / 4;
  const int N1 = N0 + NEXP * 2 * INTER * HID / 4;
  const int N2 = N1 + NEXP * HID * INTER / 4;
  int i = blockIdx.x * blockDim.x + threadIdx.x;
  int stride = gridDim.x * blockDim.x;
  for (; i < N2; i += stride) {
    const float* s; int o;
    if (i < N0) { s = hs; o = i; }
    else if (i < N1) { s = w1; o = i - N0; }
    else { s = w2; o = i - N1; }
    float4 v = reinterpret_cast<const float4*>(s)[o];
    ushort4 u;
    u.x = f2bf(v.x); u.y = f2bf(v.y); u.z = f2bf(v.z); u.w = f2bf(v.w);
    reinterpret_cast<ushort4*>(dst)[i] = u;
  }
}

// ---------------- routing: count + scan + fill + tile-list, one block ----
// ctrl ints: [0..7]=cnt  [8..15]=off  [16]=T  [32..103]=tile_e  [104..175]=tile_mt
__global__ void k_route(const int* __restrict__ ids, int* __restrict__ ctrl,
                        unsigned short* __restrict__ row_token,
                        unsigned short* __restrict__ inv_row) {
  __shared__ int cnt[NEXP], cur[NEXP];
  int t = threadIdx.x;
  if (t < NEXP) cnt[t] = 0;
  __syncthreads();
  for (int p = t; p < NPAIR; p += 512) atomicAdd(&cnt[ids[p]], 1);
  __syncthreads();
  if (t == 0) {
    int acc = 0, T = 0;
    for (int e = 0; e < NEXP; ++e) {
      cur[e] = acc;
      ctrl[e] = cnt[e];
      ctrl[8 + e] = acc;
      int nt = (cnt[e] + 127) >> 7;
      for (int m = 0; m < nt; ++m) { ctrl[32 + T] = e; ctrl[104 + T] = m; ++T; }
      acc += cnt[e];
    }
    ctrl[16] = T;
  }
  __syncthreads();
  for (int p = t; p < NPAIR; p += 512) {
    int e = ids[p];
    int pos = atomicAdd(&cur[e], 1);
    row_token[pos] = (unsigned short)(p >> 1);
    inv_row[p] = (unsigned short)pos;
  }
}

// ---- shared fragment-read macros (row&7 == lm&7 since rows are k*16+lm) ----
#define RD_A(BB) { \
  _Pragma("unroll") for (int m_ = 0; m_ < 4; ++m_) { \
    af[m_][0] = *(const bf16x8*)(smem + (BB) + aoff + m_*1024 + csw0); \
    af[m_][1] = *(const bf16x8*)(smem + (BB) + aoff + m_*1024 + csw1); } }
#define RD_B(dst, BB, boffv) { \
  _Pragma("unroll") for (int n_ = 0; n_ < 2; ++n_) { \
    dst[n_][0] = *(const bf16x8*)(smem + (BB) + (boffv) + n_*1024 + csw0); \
    dst[n_][1] = *(const bf16x8*)(smem + (BB) + (boffv) + n_*1024 + csw1); } }

// ---------------- GEMM1: gate_up + SwiGLU ----------------
// BM=128, BN=128 act-cols (256 gate_up chans), BK=64, 8 waves, 3 LDS buffers.
// Per K-tile: G phase (16 MFMA gate) + U phase (16 MFMA up); stage 6 units of
// kt+2 each G phase; counted VM6 each U phase end (kt+1's units land).
__global__ __launch_bounds__(512, 2) void k_gemm1(
    const unsigned short* __restrict__ hs,
    const unsigned short* __restrict__ w1,
    const int* __restrict__ ctrl,
    const unsigned short* __restrict__ row_token,
    unsigned short* __restrict__ act) {
  const int bid = blockIdx.x;
  const int ti = bid / 11;
  if (ti >= ctrl[16]) return;
  const int nt = bid - ti * 11;
  const int e = ctrl[32 + ti], mt = ctrl[104 + ti];
  const int rows = ctrl[e], off_e = ctrl[8 + e];
  const int n0g = nt * 128;
  const unsigned short* w1e = w1 + (size_t)e * (2 * INTER * HID);

  __shared__ unsigned short smem[SZ1 * 3];  // 144 KiB

  const int t = threadIdx.x;
  const int lane = t & 63, wv = t >> 6;
  const int wm = wv >> 2, wn = wv & 3;       // wm 0..1 (64 rows), wn 0..3 (32 acts)
  const int lm = lane & 15, hi4 = lane >> 4;
  const int aoff = (wm * 64 + lm) * 64;
  const int bgoff = 8192 + (wn * 32 + lm) * 64;
  const int buoff = 16384 + (wn * 32 + lm) * 64;
  const int csw0 = (hi4 ^ (lm & 7)) * 8;
  const int csw1 = ((4 + hi4) ^ (lm & 7)) * 8;
  const int ldst = t * 8;

  // staging sources (global pre-swizzled chunk, linear LDS dest — rule #21)
  const unsigned short* asrc[2];
#pragma unroll
  for (int i = 0; i < 2; ++i) {
    int p = i * 512 + t;
    int row = p >> 3, c = p & 7;
    int grow = mt * 128 + row;
    if (grow > rows - 1) grow = rows - 1;
    int token = row_token[off_e + grow];
    asrc[i] = hs + (size_t)token * HID + (c ^ (row & 7)) * 8;
  }
  const unsigned short* bsrc[4];
#pragma unroll
  for (int i = 0; i < 4; ++i) {
    int p = i * 512 + t;
    int cb = p >> 3, c = p & 7;
    int col = (cb < 128) ? (n0g + cb) : (INTER + n0g + cb - 128);
    bsrc[i] = w1e + (size_t)col * HID + (c ^ (cb & 7)) * 8;
  }

#define STAGE6_1(BB, kt) { \
  gload16(asrc[0] + (size_t)(kt)*64, smem + (BB) + ldst); \
  gload16(asrc[1] + (size_t)(kt)*64, smem + (BB) + 4096 + ldst); \
  gload16(bsrc[0] + (size_t)(kt)*64, smem + (BB) + 8192 + ldst); \
  gload16(bsrc[1] + (size_t)(kt)*64, smem + (BB) + 12288 + ldst); \
  gload16(bsrc[2] + (size_t)(kt)*64, smem + (BB) + 16384 + ldst); \
  gload16(bsrc[3] + (size_t)(kt)*64, smem + (BB) + 20480 + ldst); }

  f32x4 accg[4][2], accu[4][2];
#pragma unroll
  for (int m = 0; m < 4; ++m)
#pragma unroll
    for (int n = 0; n < 2; ++n) {
      accg[m][n] = (f32x4){0.f, 0.f, 0.f, 0.f};
      accu[m][n] = (f32x4){0.f, 0.f, 0.f, 0.f};
    }
  bf16x8 af[4][2], bg[2][2], bu[2][2];

  unsigned bA = 0, bB = SZ1, bC = 2 * SZ1;
  STAGE6_1(bA, 0)
  STAGE6_1(bB, 1)
  VM6; BAR;

  for (int kt = 0; kt < NKT1; ++kt) {
    // ---- G phase ----
    RD_A(bA)
    RD_B(bg, bA, bgoff)
    if (kt + 2 < NKT1) STAGE6_1(bC, kt + 2)
    BAR; LGKM0; PRIO1;
#pragma unroll
    for (int kk = 0; kk < 2; ++kk)
#pragma unroll
      for (int m = 0; m < 4; ++m)
#pragma unroll
        for (int n = 0; n < 2; ++n)
          accg[m][n] = __builtin_amdgcn_mfma_f32_16x16x32_bf16(af[m][kk], bg[n][kk], accg[m][n], 0, 0, 0);
    PRIO0; BAR;
    // ---- U phase ----
    RD_B(bu, bA, buoff)
    BAR; LGKM0; PRIO1;
#pragma unroll
    for (int kk = 0; kk < 2; ++kk)
#pragma unroll
      for (int m = 0; m < 4; ++m)
#pragma unroll
        for (int n = 0; n < 2; ++n)
          accu[m][n] = __builtin_amdgcn_mfma_f32_16x16x32_bf16(af[m][kk], bu[n][kk], accu[m][n], 0, 0, 0);
    PRIO0;
    if (kt + 2 < NKT1) { VM6; } else { VM0; }
    BAR;
    unsigned tmp = bA; bA = bB; bB = bC; bC = tmp;
  }

  // SwiGLU epilogue
#pragma unroll
  for (int m = 0; m < 4; ++m)
#pragma unroll
    for (int n = 0; n < 2; ++n) {
      int col = n0g + wn * 32 + n * 16 + lm;
#pragma unroll
      for (int j = 0; j < 4; ++j) {
        int grow = mt * 128 + wm * 64 + m * 16 + hi4 * 4 + j;
        if (grow < rows) {
          float g = accg[m][n][j];
          float u = accu[m][n][j];
          float a = g / (1.0f + __expf(-g)) * u;
          act[(size_t)(off_e + grow) * INTER + col] = f2bf(a);
        }
      }
    }
#undef STAGE6_1
}

// ---------------- GEMM2: down proj ----------------
// BM=128, BN=128, BK=64, 8 waves, 2 LDS buffers (64 KiB) -> 2 blocks/CU.
__global__ __launch_bounds__(512, 4) void k_gemm2(
    const unsigned short* __restrict__ act,
    const unsigned short* __restrict__ w2,
    const int* __restrict__ ctrl,
    unsigned short* __restrict__ eo) {
  const int bid = blockIdx.x;
  const int ti = bid >> 4;
  if (ti >= ctrl[16]) return;
  const int nt = bid & 15;
  const int e = ctrl[32 + ti], mt = ctrl[104 + ti];
  const int rows = ctrl[e], off_e = ctrl[8 + e];
  const int n0 = nt * 128;
  const unsigned short* w2e = w2 + (size_t)e * (HID * INTER);

  __shared__ unsigned short smem[SZ2 * 2];  // 64 KiB

  const int t = threadIdx.x;
  const int lane = t & 63, wv = t >> 6;
  const int wm = wv >> 2, wn = wv & 3;
  const int lm = lane & 15, hi4 = lane >> 4;
  const int aoff = (wm * 64 + lm) * 64;
  const int boff = 8192 + (wn * 32 + lm) * 64;
  const int csw0 = (hi4 ^ (lm & 7)) * 8;
  const int csw1 = ((4 + hi4) ^ (lm & 7)) * 8;
  const int ldst = t * 8;

  const unsigned short* asrc[2];
#pragma unroll
  for (int i = 0; i < 2; ++i) {
    int p = i * 512 + t;
    int row = p >> 3, c = p & 7;
    int grow = mt * 128 + row;
    if (grow > rows - 1) grow = rows - 1;
    asrc[i] = act + (size_t)(off_e + grow) * INTER + (c ^ (row & 7)) * 8;
  }
  const unsigned short* bsrc[2];
#pragma unroll
  for (int i = 0; i < 2; ++i) {
    int p = i * 512 + t;
    int cb = p >> 3, c = p & 7;
    bsrc[i] = w2e + (size_t)(n0 + cb) * INTER + (c ^ (cb & 7)) * 8;
  }

#define STAGE4_2(BB, kt) { \
  gload16(asrc[0] + (size_t)(kt)*64, smem + (BB) + ldst); \
  gload16(asrc[1] + (size_t)(kt)*64, smem + (BB) + 4096 + ldst); \
  gload16(bsrc[0] + (size_t)(kt)*64, smem + (BB) + 8192 + ldst); \
  gload16(bsrc[1] + (size_t)(kt)*64, smem + (BB) + 12288 + ldst); }

  f32x4 acc[4][2];
#pragma unroll
  for (int m = 0; m < 4; ++m)
#pragma unroll
    for (int n = 0; n < 2; ++n) acc[m][n] = (f32x4){0.f, 0.f, 0.f, 0.f};
  bf16x8 af[4][2], bf[2][2];

  unsigned cur = 0, oth = SZ2;
  STAGE4_2(cur, 0)
  VM0; BAR;

  for (int kt = 0; kt < NKT2; ++kt) {
    RD_A(cur)
    RD_B(bf, cur, boff)
    if (kt + 1 < NKT2) STAGE4_2(oth, kt + 1)
    BAR; LGKM0; PRIO1;
#pragma unroll
    for (int kk = 0; kk < 2; ++kk)
#pragma unroll
      for (int m = 0; m < 4; ++m)
#pragma unroll
        for (int n = 0; n < 2; ++n)
          acc[m][n] = __builtin_amdgcn_mfma_f32_16x16x32_bf16(af[m][kk], bf[n][kk], acc[m][n], 0, 0, 0);
    PRIO0; VM0; BAR;
    unsigned tmp = cur; cur = oth; oth = tmp;
  }

#pragma unroll
  for (int m = 0; m < 4; ++m)
#pragma unroll
    for (int n = 0; n < 2; ++n) {
      int col = n0 + wn * 32 + n * 16 + lm;
#pragma unroll
      for (int j = 0; j < 4; ++j) {
        int grow = mt * 128 + wm * 64 + m * 16 + hi4 * 4 + j;
        if (grow < rows)
          eo[(size_t)(off_e + grow) * HID + col] = f2bf(acc[m][n][j]);
      }
    }
#undef STAGE4_2
}

// ---------------- weighted combine: out = w0*eo[r0] + w1*eo[r1] ----------
__global__ void k_combine(const unsigned short* __restrict__ eo,
                          const float* __restrict__ tw,
                          const unsigned short* __restrict__ inv_row,
                          float* __restrict__ out) {
  int idx = blockIdx.x * blockDim.x + threadIdx.x;  // one bf16x8 chunk
  int tok = idx >> 8;        // HID/8 = 256 chunks per token
  int c8 = (idx & 255) * 8;
  int r0 = inv_row[tok * 2], r1 = inv_row[tok * 2 + 1];
  float w0 = tw[tok * 2], w1 = tw[tok * 2 + 1];
  bf16x8 v0 = *(const bf16x8*)(eo + (size_t)r0 * HID + c8);
  bf16x8 v1 = *(const bf16x8*)(eo + (size_t)r1 * HID + c8);
  float4 o0, o1;
  o0.x = w0 * bf2f((unsigned short)v0[0]) + w1 * bf2f((unsigned short)v1[0]);
  o0.y = w0 * bf2f((unsigned short)v0[1]) + w1 * bf2f((unsigned short)v1[1]);
  o0.z = w0 * bf2f((unsigned short)v0[2]) + w1 * bf2f((unsigned short)v1[2]);
  o0.w = w0 * bf2f((unsigned short)v0[3]) + w1 * bf2f((unsigned short)v1[3]);
  o1.x = w0 * bf2f((unsigned short)v0[4]) + w1 * bf2f((unsigned short)v1[4]);
  o1.y = w0 * bf2f((unsigned short)v0[5]) + w1 * bf2f((unsigned short)v1[5]);
  o1.z = w0 * bf2f((unsigned short)v0[6]) + w1 * bf2f((unsigned short)v1[6]);
  o1.w = w0 * bf2f((unsigned short)v0[7]) + w1 * bf2f((unsigned short)v1[7]);
  float4* op = reinterpret_cast<float4*>(out) + (size_t)tok * 512 + (idx & 255) * 2;
  op[0] = o0;
  op[1] = o1;
}

extern "C" void kernel_launch(void* const* d_in, const int* in_sizes, int n_in,
                              void* d_out, int out_size, void* d_ws, size_t ws_size,
                              hipStream_t stream) {
  const float* hs_f = (const float*)d_in[0];
  const float* w1_f = (const float*)d_in[1];
  const float* w2_f = (const float*)d_in[2];
  const float* tw   = (const float*)d_in[3];
  const int*   tids = (const int*)d_in[4];
  float* out = (float*)d_out;

  // workspace layout (bytes) — stays within the proven 178,323,712 footprint.
  char* ws = (char*)d_ws;
  unsigned short* hs_b = (unsigned short*)(ws);                   // 16,777,216
  unsigned short* w1_b = (unsigned short*)(ws + 16777216);        // 92,274,688
  unsigned short* w2_b = (unsigned short*)(ws + 109051904);       // 46,137,344
  unsigned short* act  = (unsigned short*)(ws + 155189248);       // 23,068,672
  // eo overlays w1_b (dead after gemm1): 8192*2048*2 = 33,554,432 bytes
  unsigned short* eo   = (unsigned short*)(ws + 16777216);
  int* ctrl = (int*)(ws + 178257920);                             // 1024 B
  unsigned short* row_token = (unsigned short*)(ws + 178258944);  // 16,384
  unsigned short* inv_row   = (unsigned short*)(ws + 178275328);  // 16,384

  k_route<<<1, 512, 0, stream>>>(tids, ctrl, row_token, inv_row);
  k_cvt_all<<<4096, 256, 0, stream>>>(hs_f, w1_f, w2_f, hs_b);

  // grids: worst-case 72 M-tiles (list-driven; excess blocks exit fast)
  k_gemm1<<<72 * 11, 512, 0, stream>>>(hs_b, w1_b, ctrl, row_token, act);
  k_gemm2<<<72 * 16, 512, 0, stream>>>(act, w2_b, ctrl, eo);
  k_combine<<<NTOK * HID / 8 / 256, 256, 0, stream>>>(eo, tw, inv_row, out);
}

// Round 4
// 285.577 us; speedup vs baseline: 1.5188x; 1.1388x over previous
//
#include <hip/hip_runtime.h>
#include <hip/hip_bf16.h>

#define NTOK 4096
#define HID 2048
#define INTER 1408
#define NEXP 8
#define NPAIR 8192   // NTOK * TOP_K
#define NKT1 32      // HID/64
#define NKT2 22      // INTER/64
#define SZ2 16384    // gemm2 elems/buffer: A 128x64 + B 128x64

typedef short bf16x8 __attribute__((ext_vector_type(8)));
typedef float f32x4 __attribute__((ext_vector_type(4)));

__device__ __forceinline__ unsigned short f2bf(float f) {
  unsigned u = __builtin_bit_cast(unsigned, f);
  u += 0x7fffu + ((u >> 16) & 1u);   // round-to-nearest-even
  return (unsigned short)(u >> 16);
}
__device__ __forceinline__ float bf2f(unsigned short v) {
  return __builtin_bit_cast(float, (unsigned)v << 16);
}

__device__ __forceinline__ void gload16(const void* g, void* l) {
  __builtin_amdgcn_global_load_lds(
      (const __attribute__((address_space(1))) void*)g,
      (__attribute__((address_space(3))) void*)l, 16, 0, 0);
}

// m204 bijective XCD swizzle over the LIVE grid size nwg: each XCD gets a
// contiguous chunk of virtual wg ids -> consecutive tiles (same expert's B
// panels / same A panel) land in the same XCD L2.
__device__ __forceinline__ int xcd_swz(int lin, int nwg) {
  int xcd = lin & 7, base = lin >> 3;
  int q = nwg >> 3, r = nwg & 7;
  return (xcd < r ? xcd * (q + 1) : r * (q + 1) + (xcd - r) * q) + base;
}

#define BAR __builtin_amdgcn_s_barrier()
#define LGKM0 asm volatile("s_waitcnt lgkmcnt(0)" ::: "memory")
#define VM6 asm volatile("s_waitcnt vmcnt(6)" ::: "memory")
#define VM0 asm volatile("s_waitcnt vmcnt(0)" ::: "memory")
#define PRIO1 __builtin_amdgcn_s_setprio(1)
#define PRIO0 __builtin_amdgcn_s_setprio(0)

// ---------------- fp32 -> bf16 convert (all three inputs, one launch) ----
__global__ void k_cvt_all(const float* __restrict__ hs, const float* __restrict__ w1,
                          const float* __restrict__ w2, unsigned short* __restrict__ dst) {
  const int N0 = NTOK * HID / 4;
  const int N1 = N0 + NEXP * 2 * INTER * HID / 4;
  const int N2 = N1 + NEXP * HID * INTER / 4;
  int i = blockIdx.x * blockDim.x + threadIdx.x;
  int stride = gridDim.x * blockDim.x;
  for (; i < N2; i += stride) {
    const float* s; int o;
    if (i < N0) { s = hs; o = i; }
    else if (i < N1) { s = w1; o = i - N0; }
    else { s = w2; o = i - N1; }
    float4 v = reinterpret_cast<const float4*>(s)[o];
    ushort4 u;
    u.x = f2bf(v.x); u.y = f2bf(v.y); u.z = f2bf(v.z); u.w = f2bf(v.w);
    reinterpret_cast<ushort4*>(dst)[i] = u;
  }
}

// ---------------- routing: count/scan/fill + TWO tile lists ----------------
// ctrl ints: [0..7]=cnt [8..15]=off [16]=T1 [17]=T2
//            [32..70]=t1_e [71..109]=t1_mt (BM=256, T1<=39)
//            [110..180]=t2_e [181..251]=t2_mt (BM=128, T2<=71)
__global__ void k_route(const int* __restrict__ ids, int* __restrict__ ctrl,
                        unsigned short* __restrict__ row_token,
                        unsigned short* __restrict__ inv_row) {
  __shared__ int cnt[NEXP], cur[NEXP];
  int t = threadIdx.x;
  if (t < NEXP) cnt[t] = 0;
  __syncthreads();
  for (int p = t; p < NPAIR; p += 512) atomicAdd(&cnt[ids[p]], 1);
  __syncthreads();
  if (t == 0) {
    int acc = 0, T1 = 0, T2 = 0;
    for (int e = 0; e < NEXP; ++e) {
      cur[e] = acc;
      ctrl[e] = cnt[e];
      ctrl[8 + e] = acc;
      int n1 = (cnt[e] + 255) >> 8;
      for (int m = 0; m < n1; ++m) { ctrl[32 + T1] = e; ctrl[71 + T1] = m; ++T1; }
      int n2 = (cnt[e] + 127) >> 7;
      for (int m = 0; m < n2; ++m) { ctrl[110 + T2] = e; ctrl[181 + T2] = m; ++T2; }
      acc += cnt[e];
    }
    ctrl[16] = T1;
    ctrl[17] = T2;
  }
  __syncthreads();
  for (int p = t; p < NPAIR; p += 512) {
    int e = ids[p];
    int pos = atomicAdd(&cur[e], 1);
    row_token[pos] = (unsigned short)(p >> 1);
    inv_row[p] = (unsigned short)pos;
  }
}

// ================= GEMM1: gate_up + SwiGLU (8-phase, BM=256) =================
// A: gathered hidden rows [256 x 64/step]; B: 256 gate_up chans (128 gate +
// 128 up). 8 waves (2M x 4N), wave owns 128 rows x 32 acts x {g,u}.
// LDS 128 KiB: 2 bufs x (A 256x64 + B 256x64).

#define G1_STAGE_A(BB, u, ktile) \
  gload16(asrc[(u)*2+0] + (ktile)*64, lds + (BB) + ((u)*2+0)*4096 + wvb); \
  gload16(asrc[(u)*2+1] + (ktile)*64, lds + (BB) + ((u)*2+1)*4096 + wvb);
#define G1_STAGE_B(BB, u, ktile) \
  gload16(bsrc[(u)*2+0] + (ktile)*64, lds + (BB) + 16384 + ((u)*2+0)*4096 + wvb); \
  gload16(bsrc[(u)*2+1] + (ktile)*64, lds + (BB) + 16384 + ((u)*2+1)*4096 + wvb);

#define G1_READ_A(dst, BB, mh) \
  _Pragma("unroll") for (int m_ = 0; m_ < 4; ++m_) { \
    dst[m_][0] = *(const bf16x8*)(lds + (BB) + aoff + (mh)*8192 + m_*1024 + csw0); \
    dst[m_][1] = *(const bf16x8*)(lds + (BB) + aoff + (mh)*8192 + m_*1024 + csw1); \
  }
#define G1_READ_B(dst, BB, nh) \
  _Pragma("unroll") for (int n_ = 0; n_ < 2; ++n_) { \
    dst[n_][0] = *(const bf16x8*)(lds + (BB) + boff + (nh)*8192 + n_*1024 + csw0); \
    dst[n_][1] = *(const bf16x8*)(lds + (BB) + boff + (nh)*8192 + n_*1024 + csw1); \
  }

#define G1_MMA_Q(afr, bfr, mh, nh) \
  _Pragma("unroll") for (int m_ = 0; m_ < 4; ++m_) \
  _Pragma("unroll") for (int n_ = 0; n_ < 2; ++n_) { \
    acc[(mh)*4+m_][(nh)*2+n_] = __builtin_amdgcn_mfma_f32_16x16x32_bf16(afr[m_][0], bfr[n_][0], acc[(mh)*4+m_][(nh)*2+n_], 0, 0, 0); \
    acc[(mh)*4+m_][(nh)*2+n_] = __builtin_amdgcn_mfma_f32_16x16x32_bf16(afr[m_][1], bfr[n_][1], acc[(mh)*4+m_][(nh)*2+n_], 0, 0, 0); \
  }

// 8 phases / 2 K-tiles. Stage-after-last-read; counted VM6 at phases 4, 8.
#define G1_EIGHT(kt) \
  G1_READ_A(afM0, 0, 0) G1_READ_B(bfN0, 0, 0) G1_STAGE_B(32768, 1, (kt)+1); \
  BAR; LGKM0; PRIO1; G1_MMA_Q(afM0, bfN0, 0, 0) PRIO0; BAR; \
  G1_READ_B(bfN1, 0, 1) G1_STAGE_B(0, 0, (kt)+2); \
  BAR; LGKM0; PRIO1; G1_MMA_Q(afM0, bfN1, 0, 1) PRIO0; BAR; \
  G1_READ_A(afM1, 0, 1) G1_STAGE_A(0, 0, (kt)+2); \
  BAR; LGKM0; PRIO1; G1_MMA_Q(afM1, bfN1, 1, 1) PRIO0; BAR; \
  G1_STAGE_A(0, 1, (kt)+2); \
  BAR; LGKM0; PRIO1; G1_MMA_Q(afM1, bfN0, 1, 0) PRIO0; VM6; BAR; \
  G1_READ_A(afM0, 32768, 0) G1_READ_B(bfN0, 32768, 0) G1_STAGE_B(0, 1, (kt)+2); \
  BAR; LGKM0; PRIO1; G1_MMA_Q(afM0, bfN0, 0, 0) PRIO0; BAR; \
  G1_READ_B(bfN1, 32768, 1) G1_STAGE_B(32768, 0, (kt)+3); \
  BAR; LGKM0; PRIO1; G1_MMA_Q(afM0, bfN1, 0, 1) PRIO0; BAR; \
  G1_READ_A(afM1, 32768, 1) G1_STAGE_A(32768, 0, (kt)+3); \
  BAR; LGKM0; PRIO1; G1_MMA_Q(afM1, bfN1, 1, 1) PRIO0; BAR; \
  G1_STAGE_A(32768, 1, (kt)+3); \
  BAR; LGKM0; PRIO1; G1_MMA_Q(afM1, bfN0, 1, 0) PRIO0; VM6; BAR;

#define G1_EPI(kt) \
  G1_READ_A(afM0, 0, 0) G1_READ_B(bfN0, 0, 0) G1_STAGE_B(32768, 1, (kt)+1); \
  BAR; LGKM0; PRIO1; G1_MMA_Q(afM0, bfN0, 0, 0) PRIO0; BAR; \
  G1_READ_B(bfN1, 0, 1) \
  BAR; LGKM0; PRIO1; G1_MMA_Q(afM0, bfN1, 0, 1) PRIO0; BAR; \
  G1_READ_A(afM1, 0, 1) \
  BAR; LGKM0; PRIO1; G1_MMA_Q(afM1, bfN1, 1, 1) PRIO0; BAR; \
  BAR; LGKM0; PRIO1; G1_MMA_Q(afM1, bfN0, 1, 0) PRIO0; VM0; BAR; \
  G1_READ_A(afM0, 32768, 0) G1_READ_B(bfN0, 32768, 0) \
  BAR; LGKM0; PRIO1; G1_MMA_Q(afM0, bfN0, 0, 0) PRIO0; BAR; \
  G1_READ_B(bfN1, 32768, 1) \
  BAR; LGKM0; PRIO1; G1_MMA_Q(afM0, bfN1, 0, 1) PRIO0; BAR; \
  G1_READ_A(afM1, 32768, 1) \
  BAR; LGKM0; PRIO1; G1_MMA_Q(afM1, bfN1, 1, 1) PRIO0; BAR; \
  LGKM0; PRIO1; G1_MMA_Q(afM1, bfN0, 1, 0) PRIO0;

__global__ __launch_bounds__(512, 2) void k_gemm1(
    const unsigned short* __restrict__ hs,
    const unsigned short* __restrict__ w1,
    const int* __restrict__ ctrl,
    const unsigned short* __restrict__ row_token,
    unsigned short* __restrict__ act) {
  const int T1 = ctrl[16];
  const int nwg = T1 * 11;
  const int lin = blockIdx.x;
  if (lin >= nwg) return;
  const int wg = xcd_swz(lin, nwg);
  const int ti = wg / 11;
  const int nt = wg - ti * 11;
  const int e = ctrl[32 + ti], mt = ctrl[71 + ti];
  const int rows = ctrl[e], off_e = ctrl[8 + e];
  const int n0g = nt * 128;
  const unsigned short* w1e = w1 + (size_t)e * (2 * INTER * HID);

  __shared__ unsigned short smem[65536];  // 128 KiB
  unsigned short* lds = smem;

  const int t = threadIdx.x;
  const int lane = t & 63, wv = t >> 6;
  const int wm = wv >> 2, wn = wv & 3;
  const int lm = lane & 15, hi4 = lane >> 4;
  const int wvb = (t & 448) * 8;
  const int aoff = (wm * 64 + lm) * 64;
  const int boff = 16384 + (wn * 32 + lm) * 64;
  const int csw0 = (hi4 ^ (lm & 7)) * 8;
  const int csw1 = ((4 + hi4) ^ (lm & 7)) * 8;

  // A slot p -> row r(p) = ((p>>6)&1)*128 + (p>>7)*64 + (p&63); global source
  // carries the chunk-XOR swizzle (linear LDS dest, rule #21).
  const unsigned short* asrc[4];
#pragma unroll
  for (int i = 0; i < 4; ++i) {
    int p = i * 64 + (t >> 3);
    int r = ((p >> 6) & 1) * 128 + (p >> 7) * 64 + (p & 63);
    int grow = mt * 256 + r;
    if (grow > rows - 1) grow = rows - 1;
    int token = row_token[off_e + grow];
    asrc[i] = hs + (size_t)token * HID + ((t & 7) ^ (p & 7)) * 8;
  }
  // B slot p: nh=p>>7 (0=gate,1=up), wave wns=(p&127)>>5, idx=p&31.
  const unsigned short* bsrc[4];
#pragma unroll
  for (int i = 0; i < 4; ++i) {
    int p = i * 64 + (t >> 3);
    int nh = p >> 7, wns = (p & 127) >> 5, idx = p & 31;
    int c = n0g + wns * 32 + idx + nh * INTER;
    bsrc[i] = w1e + (size_t)c * HID + ((t & 7) ^ (p & 7)) * 8;
  }

  f32x4 acc[8][4];
#pragma unroll
  for (int i = 0; i < 8; ++i)
#pragma unroll
    for (int j = 0; j < 4; ++j) acc[i][j] = (f32x4){0.f, 0.f, 0.f, 0.f};
  bf16x8 afM0[4][2], afM1[4][2], bfN0[2][2], bfN1[2][2];

  // prologue: kt0 all 4 units + kt1 first 3; drain to 6 outstanding
  G1_STAGE_B(0, 0, 0) G1_STAGE_A(0, 0, 0) G1_STAGE_A(0, 1, 0) G1_STAGE_B(0, 1, 0)
  G1_STAGE_B(32768, 0, 1) G1_STAGE_A(32768, 0, 1) G1_STAGE_A(32768, 1, 1)
  VM6; BAR;

  for (int kt = 0; kt + 3 < NKT1; kt += 2) { G1_EIGHT(kt) }
  G1_EPI(NKT1 - 2)

  // SwiGLU epilogue: gate = acc[mf][n], up = acc[mf][2+n]
#pragma unroll
  for (int mh = 0; mh < 2; ++mh)
#pragma unroll
    for (int m = 0; m < 4; ++m)
#pragma unroll
      for (int n = 0; n < 2; ++n) {
        int col = n0g + wn * 32 + n * 16 + lm;
#pragma unroll
        for (int j = 0; j < 4; ++j) {
          int grow = mt * 256 + wm * 128 + mh * 64 + m * 16 + hi4 * 4 + j;
          if (grow < rows) {
            float g = acc[mh * 4 + m][n][j];
            float u = acc[mh * 4 + m][2 + n][j];
            float a = g / (1.0f + __expf(-g)) * u;
            act[(size_t)(off_e + grow) * INTER + col] = f2bf(a);
          }
        }
      }
}

// ================= GEMM2: down proj (BM=128, BN=128, 2 blocks/CU) ==========
#define G2_RD_A(BB) { \
  _Pragma("unroll") for (int m_ = 0; m_ < 4; ++m_) { \
    af[m_][0] = *(const bf16x8*)(smem + (BB) + aoff + m_*1024 + csw0); \
    af[m_][1] = *(const bf16x8*)(smem + (BB) + aoff + m_*1024 + csw1); } }
#define G2_RD_B(BB) { \
  _Pragma("unroll") for (int n_ = 0; n_ < 2; ++n_) { \
    bfr[n_][0] = *(const bf16x8*)(smem + (BB) + boff + n_*1024 + csw0); \
    bfr[n_][1] = *(const bf16x8*)(smem + (BB) + boff + n_*1024 + csw1); } }

__global__ __launch_bounds__(512, 4) void k_gemm2(
    const unsigned short* __restrict__ act,
    const unsigned short* __restrict__ w2,
    const int* __restrict__ ctrl,
    unsigned short* __restrict__ eo) {
  const int T2 = ctrl[17];
  const int nwg = T2 * 16;
  const int lin = blockIdx.x;
  if (lin >= nwg) return;
  const int wg = xcd_swz(lin, nwg);
  const int ti = wg >> 4;
  const int nt = wg & 15;
  const int e = ctrl[110 + ti], mt = ctrl[181 + ti];
  const int rows = ctrl[e], off_e = ctrl[8 + e];
  const int n0 = nt * 128;
  const unsigned short* w2e = w2 + (size_t)e * (HID * INTER);

  __shared__ unsigned short smem[SZ2 * 2];  // 64 KiB

  const int t = threadIdx.x;
  const int lane = t & 63, wv = t >> 6;
  const int wm = wv >> 2, wn = wv & 3;
  const int lm = lane & 15, hi4 = lane >> 4;
  const int aoff = (wm * 64 + lm) * 64;
  const int boff = 8192 + (wn * 32 + lm) * 64;
  const int csw0 = (hi4 ^ (lm & 7)) * 8;
  const int csw1 = ((4 + hi4) ^ (lm & 7)) * 8;
  const int ldst = t * 8;

  const unsigned short* asrc[2];
#pragma unroll
  for (int i = 0; i < 2; ++i) {
    int p = i * 512 + t;
    int row = p >> 3, c = p & 7;
    int grow = mt * 128 + row;
    if (grow > rows - 1) grow = rows - 1;
    asrc[i] = act + (size_t)(off_e + grow) * INTER + (c ^ (row & 7)) * 8;
  }
  const unsigned short* bsrc[2];
#pragma unroll
  for (int i = 0; i < 2; ++i) {
    int p = i * 512 + t;
    int cb = p >> 3, c = p & 7;
    bsrc[i] = w2e + (size_t)(n0 + cb) * INTER + (c ^ (cb & 7)) * 8;
  }

#define G2_STAGE(BB, kt) { \
  gload16(asrc[0] + (size_t)(kt)*64, smem + (BB) + ldst); \
  gload16(asrc[1] + (size_t)(kt)*64, smem + (BB) + 4096 + ldst); \
  gload16(bsrc[0] + (size_t)(kt)*64, smem + (BB) + 8192 + ldst); \
  gload16(bsrc[1] + (size_t)(kt)*64, smem + (BB) + 12288 + ldst); }

  f32x4 acc[4][2];
#pragma unroll
  for (int m = 0; m < 4; ++m)
#pragma unroll
    for (int n = 0; n < 2; ++n) acc[m][n] = (f32x4){0.f, 0.f, 0.f, 0.f};
  bf16x8 af[4][2], bfr[2][2];

  unsigned cur = 0, oth = SZ2;
  G2_STAGE(cur, 0)
  VM0; BAR;

  for (int kt = 0; kt < NKT2; ++kt) {
    G2_RD_A(cur)
    G2_RD_B(cur)
    if (kt + 1 < NKT2) G2_STAGE(oth, kt + 1)
    BAR; LGKM0; PRIO1;
#pragma unroll
    for (int kk = 0; kk < 2; ++kk)
#pragma unroll
      for (int m = 0; m < 4; ++m)
#pragma unroll
        for (int n = 0; n < 2; ++n)
          acc[m][n] = __builtin_amdgcn_mfma_f32_16x16x32_bf16(af[m][kk], bfr[n][kk], acc[m][n], 0, 0, 0);
    PRIO0; VM0; BAR;
    unsigned tmp = cur; cur = oth; oth = tmp;
  }

#pragma unroll
  for (int m = 0; m < 4; ++m)
#pragma unroll
    for (int n = 0; n < 2; ++n) {
      int col = n0 + wn * 32 + n * 16 + lm;
#pragma unroll
      for (int j = 0; j < 4; ++j) {
        int grow = mt * 128 + wm * 64 + m * 16 + hi4 * 4 + j;
        if (grow < rows)
          eo[(size_t)(off_e + grow) * HID + col] = f2bf(acc[m][n][j]);
      }
    }
#undef G2_STAGE
}

// ---------------- weighted combine: out = w0*eo[r0] + w1*eo[r1] ----------
__global__ void k_combine(const unsigned short* __restrict__ eo,
                          const float* __restrict__ tw,
                          const unsigned short* __restrict__ inv_row,
                          float* __restrict__ out) {
  int idx = blockIdx.x * blockDim.x + threadIdx.x;  // one bf16x8 chunk
  int tok = idx >> 8;        // HID/8 = 256 chunks per token
  int c8 = (idx & 255) * 8;
  int r0 = inv_row[tok * 2], r1 = inv_row[tok * 2 + 1];
  float w0 = tw[tok * 2], w1 = tw[tok * 2 + 1];
  bf16x8 v0 = *(const bf16x8*)(eo + (size_t)r0 * HID + c8);
  bf16x8 v1 = *(const bf16x8*)(eo + (size_t)r1 * HID + c8);
  float4 o0, o1;
  o0.x = w0 * bf2f((unsigned short)v0[0]) + w1 * bf2f((unsigned short)v1[0]);
  o0.y = w0 * bf2f((unsigned short)v0[1]) + w1 * bf2f((unsigned short)v1[1]);
  o0.z = w0 * bf2f((unsigned short)v0[2]) + w1 * bf2f((unsigned short)v1[2]);
  o0.w = w0 * bf2f((unsigned short)v0[3]) + w1 * bf2f((unsigned short)v1[3]);
  o1.x = w0 * bf2f((unsigned short)v0[4]) + w1 * bf2f((unsigned short)v1[4]);
  o1.y = w0 * bf2f((unsigned short)v0[5]) + w1 * bf2f((unsigned short)v1[5]);
  o1.z = w0 * bf2f((unsigned short)v0[6]) + w1 * bf2f((unsigned short)v1[6]);
  o1.w = w0 * bf2f((unsigned short)v0[7]) + w1 * bf2f((unsigned short)v1[7]);
  float4* op = reinterpret_cast<float4*>(out) + (size_t)tok * 512 + (idx & 255) * 2;
  op[0] = o0;
  op[1] = o1;
}

extern "C" void kernel_launch(void* const* d_in, const int* in_sizes, int n_in,
                              void* d_out, int out_size, void* d_ws, size_t ws_size,
                              hipStream_t stream) {
  const float* hs_f = (const float*)d_in[0];
  const float* w1_f = (const float*)d_in[1];
  const float* w2_f = (const float*)d_in[2];
  const float* tw   = (const float*)d_in[3];
  const int*   tids = (const int*)d_in[4];
  float* out = (float*)d_out;

  // workspace layout (bytes) — same proven 178,323,712-byte footprint.
  char* ws = (char*)d_ws;
  unsigned short* hs_b = (unsigned short*)(ws);                   // 16,777,216
  unsigned short* w1_b = (unsigned short*)(ws + 16777216);        // 92,274,688
  unsigned short* w2_b = (unsigned short*)(ws + 109051904);       // 46,137,344
  unsigned short* act  = (unsigned short*)(ws + 155189248);       // 23,068,672
  // eo overlays w1_b (dead after gemm1): 8192*2048*2 = 33,554,432 bytes
  unsigned short* eo   = (unsigned short*)(ws + 16777216);
  int* ctrl = (int*)(ws + 178257920);                             // 1024 B
  unsigned short* row_token = (unsigned short*)(ws + 178258944);  // 16,384
  unsigned short* inv_row   = (unsigned short*)(ws + 178275328);  // 16,384

  k_route<<<1, 512, 0, stream>>>(tids, ctrl, row_token, inv_row);
  k_cvt_all<<<4096, 256, 0, stream>>>(hs_f, w1_f, w2_f, hs_b);

  // worst-case live tiles: T1 <= 39 (BM=256), T2 <= 71 (BM=128)
  k_gemm1<<<39 * 11, 512, 0, stream>>>(hs_b, w1_b, ctrl, row_token, act);
  k_gemm2<<<71 * 16, 512, 0, stream>>>(act, w2_b, ctrl, eo);
  k_combine<<<NTOK * HID / 8 / 256, 256, 0, stream>>>(eo, tw, inv_row, out);
}